// Round 6
// baseline (1665.887 us; speedup 1.0000x reference)
//
#include <hip/hip_runtime.h>

// ---------------------------------------------------------------------------
// LSTMSeq2Seq on MI355X (gfx950)
// fp16 MFMA with fp32 accumulate.
// Encoder: persistent kernels; groups are XCD-affine BY CONSTRUCTION via a
//   runtime XCC_ID roster (exactly 32 WGs/XCD: LDS forces 1 WG/CU and the
//   256-WG grid is co-resident). h exchange: FRESH per-step slots, PLAIN
//   stores (dirty in the XCD-shared L2, vmcnt-drained) + PLAIN loads.
// R11: 8-wave WGs -> 2 waves/SIMD TLP. Counter sync (per-(group,step) 64B
//   line, 1 atomicAdd/WG/step, all waves poll autonomously).
// R14: split-K waves (wr4 = wid&3 row-tile, ks = wid>>2 K-half), acc[4] with
//   tile n == GATE n. Halves the per-step L2 A-broadcast.
// R15: (a) in-register gates: with n==gate, each lane holds full gate
//   quadruples; the zl full round-trip is replaced by a partner-wave (wid^4)
//   HALF-exchange (8 f32/lane, one barrier) and gates computed in MFMA
//   layout. Row split: wave ks handles r = 2ks..2ks+1. One barrier and the
//   gate remap removed. (b) x loads issued BEFORE the poll: the poll's
//   atomic load inherently drains vmcnt, so the x round-trip hides under the
//   poll wait (bounded drain at poll ENTRY — not R13's spin-with-loads).
// Decoder: parallel fused kernel.
// ---------------------------------------------------------------------------

typedef _Float16 f16;
typedef _Float16 h8 __attribute__((ext_vector_type(8)));
typedef _Float16 h4 __attribute__((ext_vector_type(4)));
typedef _Float16 h2v __attribute__((ext_vector_type(2)));
typedef float f32x4 __attribute__((ext_vector_type(4)));
typedef float f32x2 __attribute__((ext_vector_type(2)));
typedef unsigned long long ull;

#define DEV static __device__ __forceinline__

constexpr int NB   = 512;   // batch
constexpr int TP   = 128;   // past steps
constexpr int TFU  = 48;    // future steps
constexpr int FIN  = 64;
constexpr int FOUT = 16;
constexpr int HS   = 512;   // hidden
constexpr int G4   = 2048;  // 4*H

DEV float sigf(float x) { return 1.0f / (1.0f + __expf(-x)); }
DEV float tanh_(float x) { float e = __expf(2.0f * x); return 1.0f - 2.0f / (e + 1.0f); }

// forced-issue loads (asm volatile cannot be sunk)
DEV void issue_ld(h8& d, const f16* p) {   // plain cached (L1/L2-shareable)
  asm volatile("global_load_dwordx4 %0, %1, off" : "=v"(d) : "v"(p));
}
DEV void issue_ldc(h8& d, const f16* p) {  // coherent (LLC-direct)
  asm volatile("global_load_dwordx4 %0, %1, off sc0 sc1" : "=v"(d) : "v"(p));
}
#define ASM_VM0    asm volatile("s_waitcnt vmcnt(0)" ::: "memory")
#define ASM_VMC(N) asm volatile("s_waitcnt vmcnt(" #N ")" ::: "memory")
#define SBAR       __builtin_amdgcn_sched_barrier(0)

DEV void st_coh_h1(f16* p, f16 v) {
  union { f16 h; unsigned short u; } c;
  c.h = v;
  __hip_atomic_store((unsigned short*)p, c.u, __ATOMIC_RELAXED, __HIP_MEMORY_SCOPE_AGENT);
}

DEV unsigned xcc_id() {
  unsigned x;
  asm("s_getreg_b32 %0, hwreg(HW_REG_XCC_ID)" : "=s"(x));
  return x & 7;
}

// interleaved z-col index ic = q*64 + gate*16 + j  <->  original zc = gate*512 + q*16 + j
DEV int ic2zc(int ic) { return ((ic >> 4) & 3) * 512 + ((ic >> 6) << 4) + (ic & 15); }

// ---------------------------------------------------------------------------
// prep kernels
// ---------------------------------------------------------------------------
__global__ void k_conv(const float* __restrict__ a, const float* __restrict__ b,
                       f16* __restrict__ a16, f16* __restrict__ b16) {
  const size_t NA = (size_t)NB * TP * FIN;
  const size_t NBT = (size_t)NB * TFU * FOUT;
  for (size_t i = (size_t)blockIdx.x * blockDim.x + threadIdx.x; i < NA + NBT;
       i += (size_t)gridDim.x * blockDim.x) {
    if (i < NA) a16[i] = (f16)a[i];
    else        b16[i - NA] = (f16)b[i - NA];
  }
}

__global__ void k_bias(const float* __restrict__ b1, const float* __restrict__ b2,
                       const float* __restrict__ b3, const float* __restrict__ b4,
                       float* __restrict__ o1, float* __restrict__ o2,
                       float* __restrict__ o3, float* __restrict__ o4) {
  int ic = blockIdx.x * blockDim.x + threadIdx.x;
  if (ic < G4) {
    int zc = ic2zc(ic);
    o1[ic] = b1[zc]; o2[ic] = b2[zc]; o3[ic] = b3[zc]; o4[ic] = b4[zc];
  }
}

// pack a (K x 2048) fp32 weight (concat of two, or sum of two) into fp16 MFMA
// B-fragment blocks: dst[((nt*NKC + kc)*64 + lane)*8 + j]
__global__ void k_pack(const float* __restrict__ A, const float* __restrict__ Bs,
                       int split, int NKC, int mode, f16* __restrict__ dst) {
  int i = blockIdx.x * blockDim.x + threadIdx.x;
  int total = 128 * NKC * 64;
  if (i >= total) return;
  int lane = i & 63, rem = i >> 6;
  int kc = rem % NKC, nt = rem / NKC;
  int zc = ic2zc(nt * 16 + (lane & 15));
  int k0 = kc * 32 + ((lane >> 4) << 3);
  h8 v;
#pragma unroll
  for (int j = 0; j < 8; j++) {
    int k = k0 + j;
    float x;
    if (mode == 2) x = A[(size_t)k * G4 + zc] + Bs[(size_t)k * G4 + zc];
    else x = (k < split) ? A[(size_t)k * G4 + zc] : Bs[(size_t)(k - split) * G4 + zc];
    v[j] = (f16)x;
  }
  *(h8*)(dst + (size_t)i * 8) = v;
}

// dec1_Wk (16 x 2048) -> 16x16x16 B frags
__global__ void k_pack_dk16(const float* __restrict__ W, f16* __restrict__ dst) {
  int i = blockIdx.x * blockDim.x + threadIdx.x;
  if (i >= 128 * 64) return;
  int lane = i & 63, nt = i >> 6;
  int zc = ic2zc(nt * 16 + (lane & 15));
  h4 v;
#pragma unroll
  for (int j = 0; j < 4; j++) v[j] = (f16)W[(size_t)(((lane >> 4) << 2) + j) * G4 + zc];
  *(h4*)(dst + (size_t)i * 4) = v;
}

// fc_W (512 x 16) -> 16x16x16 B frags
__global__ void k_pack_fc(const float* __restrict__ W, f16* __restrict__ dst) {
  int i = blockIdx.x * blockDim.x + threadIdx.x;
  if (i >= 32 * 64) return;
  int lane = i & 63, q = i >> 6;
  h4 v;
#pragma unroll
  for (int j = 0; j < 4; j++) {
    int k = q * 16 + ((lane >> 4) << 2) + j;
    v[j] = (f16)W[(size_t)k * FOUT + (lane & 15)];
  }
  *(h4*)(dst + (size_t)i * 4) = v;
}

// ---------------------------------------------------------------------------
// Encoder persistent kernel. 256 WGs = 8 XCD-groups (64 batch rows) x 32 col-WGs.
// (g, c) from XCC_ID + roster slot -> group == physical XCD.
// h buffers BLOCKED: halves offset = (cb*512 + row)*16 + col16 (cb = hcol/16).
// 8 waves/WG, split-K: wave (wr4 = wid&3, ks = wid>>2) = rows 16*wr4..+15,
// ALL 4 col-tiles (acc[4], tile n == gate n), K-half ks.
// Partner-wave (wid^4) half-exchange: each wave ships acc[n][2(ks^1)+j] (the
// rows its partner owns), one barrier, partner adds and computes gates in
// MFMA layout (lane -> rows (lane>>4)*4 + 2ks + {0,1}, col 16c + (lane&15)).
// Sync: per-(group,step) counter line. Publish: drain + barrier + atomicAdd
// (tid 0). Consume: every wave polls the single word autonomously; x loads
// issued before the poll ride its inherent vmcnt drain.
// ---------------------------------------------------------------------------
template <int L, bool HIST>
__global__ __launch_bounds__(512, 2) void k_enc(
    const f16* __restrict__ wfrag, const float* __restrict__ biasI,
    f16* __restrict__ h1s, f16* __restrict__ h2r, f16* __restrict__ h2s,
    float* __restrict__ cT, const float* __restrict__ cInit,
    const f16* __restrict__ inp16, unsigned int* __restrict__ cnt,
    int* __restrict__ roster) {
  constexpr int XKC = (L == 1) ? 2 : 16;   // x-part K chunks (K/32)
  constexpr int XKH = XKC / 2;             // x chunks per wave (split-K)
  constexpr int NKC = XKC + 16;            // total K chunks
  constexpr size_t SLOT = (size_t)NB * HS; // halves per h slot
  constexpr bool PLAIN_H = (L == 1) || HIST;

  extern __shared__ __align__(16) char smem[];
  f16* Bl = (f16*)smem;
  float* exl = (float*)(smem + (size_t)NKC * 4096); // 8 slots x 512 f32 = 16 KB
  __shared__ int s_gc[2];

  const int tid = threadIdx.x, lane = tid & 63, wid = tid >> 6;
  const int wr4 = wid & 3, ks = wid >> 2;  // row-tile, K-half

  // --- XCD roster: group = physical XCD, c = arrival slot within it ---
  if (tid == 0) {
    unsigned x = xcc_id();
    int slot = atomicAdd(&roster[x], 1) & 31;
    s_gc[0] = (int)x; s_gc[1] = slot;
  }
  __syncthreads();
  const int g = s_gc[0], c = s_gc[1];
  const int b0 = g * 64;
  const int l15 = lane & 15, lk = (lane >> 4) << 3;

  // wrap start chunk (decorrelates the per-step L2 h-broadcast burst)
  const int kc0 = ((c >> 1) + 1) & 15;

  // --- fill B fragments (once) ---
  {
    const uint4* src = (const uint4*)wfrag + (size_t)c * NKC * 256;
    uint4* dst = (uint4*)smem;
    for (int i = tid; i < NKC * 256; i += 512) dst[i] = src[i];
  }

  // --- bias regs (MFMA layout: gate n at col 16c + l15) ---
  float bv[4];
#pragma unroll
  for (int n = 0; n < 4; n++) bv[n] = biasI[64 * c + 16 * n + l15];

  // --- gate-row ownership: lane handles rows grow0, grow0+1; col 16c+l15 ---
  const int grow0 = b0 + 16 * wr4 + ((lane >> 4) << 2) + 2 * ks;

  // --- c state (2 rows per lane) ---
  float cst[2];
  if (L == 1) {
    cst[0] = cst[1] = 0.0f;
  } else {
#pragma unroll
    for (int j = 0; j < 2; j++)
      cst[j] = cInit[(size_t)(grow0 + j) * HS + 16 * c + l15];
  }

  const int arow = b0 + 16 * wr4 + l15;

  // all 4 col-tiles of this WG (tile n == gate n)
  const f16* bbase[4];
#pragma unroll
  for (int n = 0; n < 4; n++) bbase[n] = Bl + ((size_t)n * NKC * 64 + lane) * 8;

  // per-lane blocked-layout A offset (halves): ((lk>>4)*512 + row)*16 + (lk&8)
  const size_t aoff = ((size_t)(lk >> 4) * 512 + arow) * 16 + (lk & 8);

  unsigned int* cbase = cnt + (size_t)g * TP * 16; // 64B line per (g,t)

  const int myslot = wr4 * 2 + ks, pslot = wr4 * 2 + (ks ^ 1);
  const int j2p = 2 * (ks ^ 1); // partner's rows within acc regs

  __syncthreads();

  for (int t = 0; t < TP; t++) {
    // ---- forced-issue x-part A loads (this wave's K-half only).
    //      Issued BEFORE the poll: the poll's atomic load drains vmcnt, so
    //      the x round-trip rides the poll wait. ----
    h8 ax[XKH];
    if (L == 1) {
      const f16* xb = inp16 + ((size_t)arow * TP + t) * FIN + lk + ks * 32;
      issue_ld(ax[0], xb);
    } else {
      const f16* xp = h1s + (size_t)(t + 1) * SLOT + aoff + (size_t)ks * XKH * 16384;
#pragma unroll
      for (int kc = 0; kc < XKH; kc++) {
        issue_ld(ax[kc], xp);
        xp += 16384;
      }
    }

    // ---- wait: all 32 WGs of this group published step t-1 (single word,
    //      every wave autonomously). First poll iteration drains x loads. ----
    if (t > 0) {
      const unsigned int* cp = cbase + (size_t)(t - 1) * 16;
      while (__hip_atomic_load(cp, __ATOMIC_RELAXED, __HIP_MEMORY_SCOPE_AGENT) < 32u)
        __builtin_amdgcn_s_sleep(1);
      SBAR; // nothing (esp. h loads) moves above the poll
    } else {
      ASM_VM0; SBAR; // t==0: no poll; land x explicitly
    }

    // ---- h base (blocked layout) ----
    const f16* hb;
    if (L == 1) hb = h1s + (size_t)t * SLOT;
    else if (HIST) hb = (t == 0) ? (h1s + (size_t)TP * SLOT) : (h2s + (size_t)(t - 1) * SLOT);
    else hb = (t == 0) ? (h1s + (size_t)TP * SLOT) : (h2r + (size_t)((t - 1) & 1) * SLOT);
    const f16* hpb = hb + aoff;

    h8 hA[4], hB[4];
#define LD_H(D, P) { if constexpr (PLAIN_H) issue_ld(D, P); else issue_ldc(D, P); }
#define HB_ISSUE4(R, P)                                                        \
  {                                                                            \
    _Pragma("unroll") for (int j = 0; j < 4; j++) {                            \
      int kk = (kc0 + 8 * ks + (P) + j) & 15;                                  \
      const f16* q = hpb + (size_t)kk * 16384;                                 \
      LD_H(R[j], q)                                                            \
    }                                                                          \
  }
#define HB_MFMA4(R, P)                                                         \
  {                                                                            \
    _Pragma("unroll") for (int j = 0; j < 4; j++) {                            \
      int kk = (kc0 + 8 * ks + (P) + j) & 15;                                  \
      _Pragma("unroll") for (int n = 0; n < 4; n++) {                          \
        h8 bb = *(const h8*)(bbase[n] + (size_t)(XKC + kk) * 512);             \
        acc[n] = __builtin_amdgcn_mfma_f32_16x16x32_f16(R[j], bb, acc[n], 0, 0, 0); \
      }                                                                        \
    }                                                                          \
  }

    // ---- issue all 8 h loads of this wave ----
    HB_ISSUE4(hA, 0)
    HB_ISSUE4(hB, 4)

    f32x4 acc[4] = {};

    // ---- x-part MFMA (covers h flight; ax already landed) ----
#pragma unroll
    for (int kc = 0; kc < XKH; kc++) {
      int kg = ks * XKH + kc;
#pragma unroll
      for (int n = 0; n < 4; n++) {
        h8 bb = *(const h8*)(bbase[n] + (size_t)kg * 512);
        acc[n] = __builtin_amdgcn_mfma_f32_16x16x32_f16(ax[kc], bb, acc[n], 0, 0, 0);
      }
    }

    // ---- h-part: 2-round counted-vmcnt ladder ----
    ASM_VMC(4); SBAR;
    HB_MFMA4(hA, 0)
    ASM_VMC(0); SBAR;
    HB_MFMA4(hB, 4)
#undef HB_ISSUE4
#undef HB_MFMA4
#undef LD_H

    // ---- partner-wave half-exchange: ship the rows the partner owns ----
#pragma unroll
    for (int n = 0; n < 4; n++)
#pragma unroll
      for (int j = 0; j < 2; j++)
        exl[(size_t)myslot * 512 + (size_t)(n * 2 + j) * 64 + lane] = acc[n][j2p + j];
    __syncthreads();

    // ---- gates in MFMA layout (rows grow0..+1, col 16c + l15) ----
    f16 hval[2];
#pragma unroll
    for (int j = 0; j < 2; j++) {
      float zi = acc[0][2 * ks + j] + exl[(size_t)pslot * 512 + (size_t)(0 + j) * 64 + lane] + bv[0];
      float zf = acc[1][2 * ks + j] + exl[(size_t)pslot * 512 + (size_t)(2 + j) * 64 + lane] + bv[1];
      float zg = acc[2][2 * ks + j] + exl[(size_t)pslot * 512 + (size_t)(4 + j) * 64 + lane] + bv[2];
      float zo = acc[3][2 * ks + j] + exl[(size_t)pslot * 512 + (size_t)(6 + j) * 64 + lane] + bv[3];
      float ci = sigf(zf) * cst[j] + sigf(zi) * tanh_(zg);
      cst[j] = ci;
      hval[j] = (f16)(sigf(zo) * tanh_(ci));
    }
    {
      f16* hsl;
      if (L == 1) hsl = h1s + (size_t)(t + 1) * SLOT;
      else if (HIST) hsl = h2s + (size_t)t * SLOT;
      else hsl = h2r + (size_t)(t & 1) * SLOT;
#pragma unroll
      for (int j = 0; j < 2; j++) {
        f16* hp = hsl + ((size_t)c * 512 + grow0 + j) * 16 + l15;
        // XCD-affine path: plain store -> dirty in this XCD's L2.
        if constexpr (PLAIN_H) *hp = hval[j];
        else st_coh_h1(hp, hval[j]); // fallback ring: write-through LLC
      }
    }
    if (t == TP - 1) {
#pragma unroll
      for (int j = 0; j < 2; j++)
        cT[(size_t)(grow0 + j) * HS + 16 * c + l15] = cst[j];
    }

    // ---- publish: drain stores (to L2/LLC), barrier, count ourselves in ----
    ASM_VM0;
    __syncthreads();
    if (tid == 0)
      __hip_atomic_fetch_add(cbase + (size_t)t * 16, 1u, __ATOMIC_RELAXED,
                             __HIP_MEMORY_SCOPE_AGENT);
  }
}

// ---------------------------------------------------------------------------
// Decoder: u = h2T @ dec1_Wr + dec1_b. h2T = final h2 slot base (blocked).
// ---------------------------------------------------------------------------
__global__ __launch_bounds__(256) void k_d1(const f16* __restrict__ h2T,
                                            const f16* __restrict__ wF,
                                            const float* __restrict__ bI,
                                            float* __restrict__ u) {
  const int tid = threadIdx.x, lane = tid & 63, wid = tid >> 6;
  const int wr = wid & 1, wc = wid >> 1;
  const int r0 = (blockIdx.x >> 4) * 32, ic0 = (blockIdx.x & 15) * 128;
  const int l15 = lane & 15, lk = (lane >> 4) << 3;
  const int arow = r0 + 16 * wr + l15;
  const f16* abase = h2T + ((size_t)(lk >> 4) * 512 + arow) * 16 + (lk & 8);
  const int nt0 = (ic0 >> 4) + 4 * wc;
  f32x4 acc[4] = {};
#pragma unroll
  for (int kc = 0; kc < 16; kc++) {
    h8 a = *(const h8*)(abase + (size_t)kc * 16384);
#pragma unroll
    for (int n = 0; n < 4; n++) {
      h8 b = *(const h8*)(wF + ((size_t)(nt0 + n) * 16 + kc) * 512 + (size_t)lane * 8);
      acc[n] = __builtin_amdgcn_mfma_f32_16x16x32_f16(a, b, acc[n], 0, 0, 0);
    }
  }
#pragma unroll
  for (int n = 0; n < 4; n++)
#pragma unroll
    for (int r = 0; r < 4; r++) {
      int row = r0 + 16 * wr + ((lane >> 4) << 2) + r;
      int ic = ic0 + 64 * wc + 16 * n + l15;
      u[(size_t)row * G4 + ic] = acc[n][r] + bI[ic];
    }
}

// ---------------------------------------------------------------------------
// Fused decoder: per-WG 64 (b,t) rows.
// ---------------------------------------------------------------------------
__global__ __launch_bounds__(256, 1) void k_d2(
    const f16* __restrict__ tg16, const f16* __restrict__ wk16F,
    const float* __restrict__ u, const float* __restrict__ c2T,
    const f16* __restrict__ w2F, const float* __restrict__ b2I,
    const f16* __restrict__ fcF, const float* __restrict__ fcb,
    float* __restrict__ out) {
  extern __shared__ __align__(16) char smem[];
  constexpr size_t H1OFF = 0;       // 64x512 f16, XOR-swizzled (65536 B)
  constexpr size_t C1OFF = 65536;   // 64x512 f16 (65536 B)
  constexpr size_t H2OFF = 131072;  // 4 waves x 64 x 24 f16 (12288 B)
  constexpr size_t RDOFF = 143360;  // 4 waves x 64 x 18 f32 (18432 B)

  const int tid = threadIdx.x, lane = tid & 63, wid = tid >> 6;
  const int l15 = lane & 15;
  const int r0 = blockIdx.x * 64;

  // ---- stage 1 ----
  {
    const int wr = wid & 1, wc = wid >> 1;
    h4 a[2];
#pragma unroll
    for (int m = 0; m < 2; m++)
      a[m] = *(const h4*)(tg16 + (size_t)(r0 + 32 * wr + 16 * m + l15) * FOUT +
                          ((lane >> 4) << 2));
#pragma unroll 1
    for (int hc = 0; hc < 8; hc++) {
      f32x4 acc[2][8] = {};
#pragma unroll
      for (int n = 0; n < 8; n++) {
        int ntg = 16 * hc + 8 * wc + n;
        h4 b = *(const h4*)(wk16F + ((size_t)ntg * 64 + lane) * 4);
        acc[0][n] = __builtin_amdgcn_mfma_f32_16x16x16f16(a[0], b, acc[0][n], 0, 0, 0);
        acc[1][n] = __builtin_amdgcn_mfma_f32_16x16x16f16(a[1], b, acc[1][n], 0, 0, 0);
      }
#pragma unroll
      for (int m = 0; m < 2; m++)
#pragma unroll
        for (int s = 0; s < 2; s++) {
          int qq = 4 * hc + 2 * wc + s;
          int colh = 16 * qq + l15;
          int icb = 256 * hc + 128 * wc + 64 * s + l15;
#pragma unroll
          for (int r = 0; r < 4; r++) {
            int rl = 32 * wr + 16 * m + ((lane >> 4) << 2) + r;
            int grow = r0 + rl;
            int bidx = grow / 48;
            const float* ub = u + (size_t)bidx * G4;
            float zi = acc[m][4 * s + 0][r] + ub[icb];
            float zf = acc[m][4 * s + 1][r] + ub[icb + 16];
            float zg = acc[m][4 * s + 2][r] + ub[icb + 32];
            float zo = acc[m][4 * s + 3][r] + ub[icb + 48];
            float c2v = c2T[(size_t)bidx * HS + colh];
            float c1 = sigf(zf) * c2v + sigf(zi) * tanh_(zg);
            float h1 = sigf(zo) * tanh_(c1);
            size_t hb = (((size_t)rl * 1024) + (size_t)colh * 2) ^ (size_t)((rl & 7) << 4);
            *(f16*)(smem + H1OFF + hb) = (f16)h1;
            *(f16*)(smem + C1OFF + (size_t)rl * 1024 + (size_t)colh * 2) = (f16)c1;
          }
        }
    }
  }
  __syncthreads();

  // ---- stage 2 + fc ----
  {
    const int w = wid;
    f32x4 facc[4] = {};
#pragma unroll 1
    for (int sc = 0; sc < 8; sc++) {
      f32x4 acc[4][4] = {};
#pragma unroll
      for (int kc = 0; kc < 16; kc++) {
        h8 a[4];
#pragma unroll
        for (int mt = 0; mt < 4; mt++) {
          int rl = 16 * mt + l15;
          size_t ab = (((size_t)rl * 1024) + (size_t)(kc * 32 + ((lane >> 4) << 3)) * 2) ^
                      (size_t)((rl & 7) << 4);
          a[mt] = *(const h8*)(smem + H1OFF + ab);
        }
#pragma unroll
        for (int n = 0; n < 4; n++) {
          int nt = 32 * w + 4 * sc + n;
          h8 b = *(const h8*)(w2F + ((size_t)nt * 16 + kc) * 512 + (size_t)lane * 8);
#pragma unroll
          for (int mt = 0; mt < 4; mt++)
            acc[mt][n] = __builtin_amdgcn_mfma_f32_16x16x32_f16(a[mt], b, acc[mt][n], 0, 0, 0);
        }
      }
      int qq = 8 * w + sc;
#pragma unroll
      for (int mt = 0; mt < 4; mt++)
#pragma unroll
        for (int r = 0; r < 4; r++) {
          int rl = 16 * mt + ((lane >> 4) << 2) + r;
          int colh = 16 * qq + l15;
          int ic = 512 * w + 64 * sc + l15;
          float zi = acc[mt][0][r] + b2I[ic];
          float zf = acc[mt][1][r] + b2I[ic + 16];
          float zg = acc[mt][2][r] + b2I[ic + 32];
          float zo = acc[mt][3][r] + b2I[ic + 48];
          float c1v = (float)*(const f16*)(smem + C1OFF + (size_t)rl * 1024 + (size_t)colh * 2);
          float cn = sigf(zf) * c1v + sigf(zi) * tanh_(zg);
          float h2v_ = sigf(zo) * tanh_(cn);
          *(f16*)(smem + H2OFF + (size_t)w * 3072 + (size_t)rl * 48 + (size_t)l15 * 2) = (f16)h2v_;
        }
      // fc partial for this 16-col block
#pragma unroll
      for (int mt = 0; mt < 4; mt++) {
        h4 aa = *(const h4*)(smem + H2OFF + (size_t)w * 3072 + (size_t)(16 * mt + l15) * 48 +
                             ((lane >> 4) << 3));
        h4 bb = *(const h4*)(fcF + ((size_t)qq * 64 + lane) * 4);
        facc[mt] = __builtin_amdgcn_mfma_f32_16x16x16f16(aa, bb, facc[mt], 0, 0, 0);
      }
    }
#pragma unroll
    for (int mt = 0; mt < 4; mt++)
#pragma unroll
      for (int r = 0; r < 4; r++) {
        int rl = 16 * mt + ((lane >> 4) << 2) + r;
        *(float*)(smem + RDOFF + ((size_t)w * 1152 + (size_t)rl * 18 + l15) * 4) = facc[mt][r];
      }
  }
  __syncthreads();

  // ---- cross-wave reduce + output ----
  {
    int rl = tid >> 2, c4 = (tid & 3) * 4;
    f32x4 o;
#pragma unroll
    for (int j = 0; j < 4; j++) {
      float s = 0.0f;
#pragma unroll
      for (int w = 0; w < 4; w++)
        s += *(const float*)(smem + RDOFF + ((size_t)w * 1152 + (size_t)rl * 18 + c4 + j) * 4);
      o[j] = s + fcb[c4 + j];
    }
    *(f32x4*)(out + (size_t)(r0 + rl) * FOUT + c4) = o;
  }
}

// ---------------------------------------------------------------------------
// host
// ---------------------------------------------------------------------------
extern "C" void kernel_launch(void* const* d_in, const int* in_sizes, int n_in,
                              void* d_out, int out_size, void* d_ws, size_t ws_size,
                              hipStream_t stream) {
  const float* inp     = (const float*)d_in[0];
  const float* target  = (const float*)d_in[1];
  const float* e1Wk    = (const float*)d_in[2];
  const float* e1Wr    = (const float*)d_in[3];
  const float* e1b     = (const float*)d_in[4];
  const float* e2Wk    = (const float*)d_in[5];
  const float* e2Wr    = (const float*)d_in[6];
  const float* e2b     = (const float*)d_in[7];
  const float* d1Wk    = (const float*)d_in[8];
  const float* d1Wr    = (const float*)d_in[9];
  const float* d1b     = (const float*)d_in[10];
  const float* d2Wk    = (const float*)d_in[11];
  const float* d2Wr    = (const float*)d_in[12];
  const float* d2b     = (const float*)d_in[13];
  const float* fcW     = (const float*)d_in[14];
  const float* fcb     = (const float*)d_in[15];
  float* out = (float*)d_out;

  // ---- workspace carve ----
  char* ws = (char*)d_ws;
  size_t off = 0;
  auto carve = [&](size_t bytes) { char* p = ws + off; off += bytes; return p; };
  f16*   inp16 = (f16*)carve((size_t)NB * TP * FIN * 2);        // 8.39 MB
  f16*   tg16  = (f16*)carve((size_t)NB * TFU * FOUT * 2);      // 0.79 MB
  f16*   h1s   = (f16*)carve((size_t)(TP + 1) * NB * HS * 2);   // 67.6 MB (blocked slots)
  f16*   h2r   = (f16*)carve((size_t)2 * NB * HS * 2);          // 1 MB (blocked ring)
  float* c1T   = (float*)carve((size_t)NB * HS * 4);
  float* c2T   = (float*)carve((size_t)NB * HS * 4);
  float* ubuf  = (float*)carve((size_t)NB * G4 * 4);            // 4 MB
  f16*   Wc1F  = (f16*)carve((size_t)576 * G4 * 2);
  f16*   Wc2F  = (f16*)carve((size_t)1024 * G4 * 2);
  f16*   d1WrF = (f16*)carve((size_t)512 * G4 * 2);
  f16*   W2sF  = (f16*)carve((size_t)512 * G4 * 2);
  f16*   dk16F = (f16*)carve((size_t)16 * G4 * 2);
  f16*   fcWF  = (f16*)carve((size_t)512 * FOUT * 2);
  float* eB1I  = (float*)carve((size_t)G4 * 4);
  float* eB2I  = (float*)carve((size_t)G4 * 4);
  float* dB1I  = (float*)carve((size_t)G4 * 4);
  float* dB2I  = (float*)carve((size_t)G4 * 4);
  // per-(group,step) publish counters, one 64B line each: [layer][8][TP]
  unsigned int* cnt1 = (unsigned int*)carve((size_t)8 * TP * 64);
  unsigned int* cnt2 = (unsigned int*)carve((size_t)8 * TP * 64);
  int*   roster = (int*)carve(256);                             // [0..7] L1, [8..15] L2 (+pad)
  // optional 128-slot h2 history (enables L2-shared plain h loads in enc2)
  const size_t H2S_BYTES = (size_t)TP * NB * HS * 2;            // 67.1 MB
  bool hist = (ws_size >= off + H2S_BYTES);
  f16* h2s = hist ? (f16*)carve(H2S_BYTES) : nullptr;
  (void)n_in; (void)in_sizes; (void)out_size;

  constexpr int LDS_E1 = 18 * 4096 + 64 * 68 * 4;  // 91136
  constexpr int LDS_E2 = 32 * 4096 + 64 * 68 * 4;  // 148480
  constexpr int LDS_D2 = 143360 + 18432;           // 161792
  {
    void (*p1)(const f16*, const float*, f16*, f16*, f16*, float*, const float*, const f16*,
               unsigned int*, int*) = k_enc<1, true>;
    void (*p2a)(const f16*, const float*, f16*, f16*, f16*, float*, const float*, const f16*,
                unsigned int*, int*) = k_enc<2, true>;
    void (*p2b)(const f16*, const float*, f16*, f16*, f16*, float*, const float*, const f16*,
                unsigned int*, int*) = k_enc<2, false>;
    hipFuncSetAttribute((const void*)p1, hipFuncAttributeMaxDynamicSharedMemorySize, LDS_E1);
    hipFuncSetAttribute((const void*)p2a, hipFuncAttributeMaxDynamicSharedMemorySize, LDS_E2);
    hipFuncSetAttribute((const void*)p2b, hipFuncAttributeMaxDynamicSharedMemorySize, LDS_E2);
    hipFuncSetAttribute((const void*)k_d2, hipFuncAttributeMaxDynamicSharedMemorySize, LDS_D2);
  }

  // init: counters + roster = 0 (every launch: graph-replay safe),
  //       h1s slot 0 = zeros (initial hidden state)
  hipMemsetAsync(cnt1, 0, (size_t)2 * 8 * TP * 64 + 256, stream);
  hipMemsetAsync(h1s, 0, (size_t)NB * HS * 2, stream);

  // prep
  k_conv<<<4096, 256, 0, stream>>>(inp, target, inp16, tg16);
  k_bias<<<8, 256, 0, stream>>>(e1b, e2b, d1b, d2b, eB1I, eB2I, dB1I, dB2I);
  k_pack<<<576, 256, 0, stream>>>(e1Wk, e1Wr, 64, 18, 1, Wc1F);    // [Wk1;Wr1] K=576
  k_pack<<<1024, 256, 0, stream>>>(e2Wk, e2Wr, 512, 32, 1, Wc2F);  // [Wk2;Wr2] K=1024
  k_pack<<<512, 256, 0, stream>>>(d1Wr, d1Wr, 512, 16, 1, d1WrF);  // dec1_Wr K=512
  k_pack<<<512, 256, 0, stream>>>(d2Wk, d2Wr, 0, 16, 2, W2sF);     // dec2_Wk+dec2_Wr
  k_pack_dk16<<<32, 256, 0, stream>>>(d1Wk, dk16F);
  k_pack_fc<<<8, 256, 0, stream>>>(fcW, fcWF);

  // encoder (sequential by data dependence: L2 init state = L1 final state)
  k_enc<1, true><<<256, 512, LDS_E1, stream>>>(Wc1F, eB1I, h1s, h2r, h2s, c1T, nullptr,
                                               inp16, cnt1, roster);
  int* roster2 = roster + 8;
  if (hist)
    k_enc<2, true><<<256, 512, LDS_E2, stream>>>(Wc2F, eB2I, h1s, h2r, h2s, c2T, c1T,
                                                 nullptr, cnt2, roster2);
  else
    k_enc<2, false><<<256, 512, LDS_E2, stream>>>(Wc2F, eB2I, h1s, h2r, h2s, c2T, c1T,
                                                  nullptr, cnt2, roster2);

  // decoder
  const f16* h2T = hist ? (h2s + (size_t)(TP - 1) * NB * HS) : (h2r + (size_t)1 * NB * HS);
  k_d1<<<256, 256, 0, stream>>>(h2T, d1WrF, dB1I, ubuf);
  k_d2<<<384, 256, LDS_D2, stream>>>(tg16, dk16F, ubuf, c2T, W2sF, dB2I, fcWF, fcb, out);
}

// Round 7
// 1257.806 us; speedup vs baseline: 1.3244x; 1.3244x over previous
//
#include <hip/hip_runtime.h>

// ---------------------------------------------------------------------------
// LSTMSeq2Seq on MI355X (gfx950)
// fp16 MFMA with fp32 accumulate.
// Encoder: persistent kernels; groups are XCD-affine BY CONSTRUCTION via a
//   runtime XCC_ID roster (exactly 32 WGs/XCD: LDS forces 1 WG/CU and the
//   256-WG grid is co-resident — proven by R2-R9 spin protocols making
//   progress). h exchange: FRESH per-step slots, PLAIN stores (dirty in the
//   XCD-shared L2, vmcnt-drained) + PLAIN loads (no stale copy can exist for
//   a never-touched slot; served by the same L2).
// R11 (BEST MEASURED: 1259 us total; enc2 578 us; stable across passes):
//   8-wave WGs (512 thr) -> 2 waves/SIMD for TLP latency hiding. Wave =
//   (row-tile, col-pair), full K per wave -> acc[2], no partial sums.
//   Sync: per-(group,step) COUNTER in its own 64B line (1 atomicAdd/WG/step,
//   single-word poll, all waves autonomously). x-MFMA before the poll
//   (prior-dispatch data) hides under publish->detect window.
//   [Post-R11 experiments, all reverted: R12 relay-poll+16-burst (regressed),
//    R13 x-prefetch across poll (vector-load poll drains vmcnt -> pathological),
//    R14 split-K (typ. -3% on enc2 but outlier-prone; enc1 regressed),
//    R15 in-register gates (2-byte scattered h stores wrecked coalescing).]
// Decoder: parallel fused kernel.
// ---------------------------------------------------------------------------

typedef _Float16 f16;
typedef _Float16 h8 __attribute__((ext_vector_type(8)));
typedef _Float16 h4 __attribute__((ext_vector_type(4)));
typedef _Float16 h2v __attribute__((ext_vector_type(2)));
typedef float f32x4 __attribute__((ext_vector_type(4)));
typedef float f32x2 __attribute__((ext_vector_type(2)));
typedef unsigned long long ull;

#define DEV static __device__ __forceinline__

constexpr int NB   = 512;   // batch
constexpr int TP   = 128;   // past steps
constexpr int TFU  = 48;    // future steps
constexpr int FIN  = 64;
constexpr int FOUT = 16;
constexpr int HS   = 512;   // hidden
constexpr int G4   = 2048;  // 4*H

DEV float sigf(float x) { return 1.0f / (1.0f + __expf(-x)); }
DEV float tanh_(float x) { float e = __expf(2.0f * x); return 1.0f - 2.0f / (e + 1.0f); }

// forced-issue loads (asm volatile cannot be sunk)
DEV void issue_ld(h8& d, const f16* p) {   // plain cached (L1/L2-shareable)
  asm volatile("global_load_dwordx4 %0, %1, off" : "=v"(d) : "v"(p));
}
DEV void issue_ldc(h8& d, const f16* p) {  // coherent (LLC-direct)
  asm volatile("global_load_dwordx4 %0, %1, off sc0 sc1" : "=v"(d) : "v"(p));
}
#define ILDX(dst, base, B) \
  asm volatile("global_load_dwordx4 %0, %1, off offset:" #B : "=v"(dst) : "v"(base));
#define ASM_VM0    asm volatile("s_waitcnt vmcnt(0)" ::: "memory")
#define ASM_VMC(N) asm volatile("s_waitcnt vmcnt(" #N ")" ::: "memory")
#define SBAR       __builtin_amdgcn_sched_barrier(0)

DEV void st_coh_h2(f16* p, h2v v) {
  union { h2v h; unsigned u; } c;
  c.h = v;
  __hip_atomic_store((unsigned*)p, c.u, __ATOMIC_RELAXED, __HIP_MEMORY_SCOPE_AGENT);
}

DEV unsigned xcc_id() {
  unsigned x;
  asm("s_getreg_b32 %0, hwreg(HW_REG_XCC_ID)" : "=s"(x));
  return x & 7;
}

// interleaved z-col index ic = q*64 + gate*16 + j  <->  original zc = gate*512 + q*16 + j
DEV int ic2zc(int ic) { return ((ic >> 4) & 3) * 512 + ((ic >> 6) << 4) + (ic & 15); }

// ---------------------------------------------------------------------------
// prep kernels
// ---------------------------------------------------------------------------
__global__ void k_conv(const float* __restrict__ a, const float* __restrict__ b,
                       f16* __restrict__ a16, f16* __restrict__ b16) {
  const size_t NA = (size_t)NB * TP * FIN;
  const size_t NBT = (size_t)NB * TFU * FOUT;
  for (size_t i = (size_t)blockIdx.x * blockDim.x + threadIdx.x; i < NA + NBT;
       i += (size_t)gridDim.x * blockDim.x) {
    if (i < NA) a16[i] = (f16)a[i];
    else        b16[i - NA] = (f16)b[i - NA];
  }
}

__global__ void k_bias(const float* __restrict__ b1, const float* __restrict__ b2,
                       const float* __restrict__ b3, const float* __restrict__ b4,
                       float* __restrict__ o1, float* __restrict__ o2,
                       float* __restrict__ o3, float* __restrict__ o4) {
  int ic = blockIdx.x * blockDim.x + threadIdx.x;
  if (ic < G4) {
    int zc = ic2zc(ic);
    o1[ic] = b1[zc]; o2[ic] = b2[zc]; o3[ic] = b3[zc]; o4[ic] = b4[zc];
  }
}

// pack a (K x 2048) fp32 weight (concat of two, or sum of two) into fp16 MFMA
// B-fragment blocks: dst[((nt*NKC + kc)*64 + lane)*8 + j]
__global__ void k_pack(const float* __restrict__ A, const float* __restrict__ Bs,
                       int split, int NKC, int mode, f16* __restrict__ dst) {
  int i = blockIdx.x * blockDim.x + threadIdx.x;
  int total = 128 * NKC * 64;
  if (i >= total) return;
  int lane = i & 63, rem = i >> 6;
  int kc = rem % NKC, nt = rem / NKC;
  int zc = ic2zc(nt * 16 + (lane & 15));
  int k0 = kc * 32 + ((lane >> 4) << 3);
  h8 v;
#pragma unroll
  for (int j = 0; j < 8; j++) {
    int k = k0 + j;
    float x;
    if (mode == 2) x = A[(size_t)k * G4 + zc] + Bs[(size_t)k * G4 + zc];
    else x = (k < split) ? A[(size_t)k * G4 + zc] : Bs[(size_t)(k - split) * G4 + zc];
    v[j] = (f16)x;
  }
  *(h8*)(dst + (size_t)i * 8) = v;
}

// dec1_Wk (16 x 2048) -> 16x16x16 B frags
__global__ void k_pack_dk16(const float* __restrict__ W, f16* __restrict__ dst) {
  int i = blockIdx.x * blockDim.x + threadIdx.x;
  if (i >= 128 * 64) return;
  int lane = i & 63, nt = i >> 6;
  int zc = ic2zc(nt * 16 + (lane & 15));
  h4 v;
#pragma unroll
  for (int j = 0; j < 4; j++) v[j] = (f16)W[(size_t)(((lane >> 4) << 2) + j) * G4 + zc];
  *(h4*)(dst + (size_t)i * 4) = v;
}

// fc_W (512 x 16) -> 16x16x16 B frags
__global__ void k_pack_fc(const float* __restrict__ W, f16* __restrict__ dst) {
  int i = blockIdx.x * blockDim.x + threadIdx.x;
  if (i >= 32 * 64) return;
  int lane = i & 63, q = i >> 6;
  h4 v;
#pragma unroll
  for (int j = 0; j < 4; j++) {
    int k = q * 16 + ((lane >> 4) << 2) + j;
    v[j] = (f16)W[(size_t)k * FOUT + (lane & 15)];
  }
  *(h4*)(dst + (size_t)i * 4) = v;
}

// ---------------------------------------------------------------------------
// Encoder persistent kernel. 256 WGs = 8 XCD-groups (64 batch rows) x 32 col-WGs.
// (g, c) from XCC_ID + roster slot -> group == physical XCD.
// h buffers BLOCKED: halves offset = (cb*512 + row)*16 + col16 (cb = hcol/16).
// 8 waves/WG: wave (wr4, wc) = rows 16*wr4..+15, col-tiles {2wc, 2wc+1},
// full K -> acc[2]. 2 waves/SIMD hide load/dep latency.
// L==1: h history = h1s slots 0..128 (fresh slot/step -> PLAIN stores+loads).
// L==2 HIST: h history = h2s slots 0..127 (fresh -> PLAIN). t=0 from h1s[TP].
// L==2 !HIST: h ring h2r[2] (stale-prone -> agent stores + sc0sc1 loads).
// Sync: per-(group,step) counter in its own 64B line. Publish: drain + barrier
// + one atomicAdd (tid 0). Consume: each wave polls the single word < 32.
// ---------------------------------------------------------------------------
template <int L, bool HIST>
__global__ __launch_bounds__(512, 2) void k_enc(
    const f16* __restrict__ wfrag, const float* __restrict__ biasI,
    f16* __restrict__ h1s, f16* __restrict__ h2r, f16* __restrict__ h2s,
    float* __restrict__ cT, const float* __restrict__ cInit,
    const f16* __restrict__ inp16, unsigned int* __restrict__ cnt,
    int* __restrict__ roster) {
  constexpr int XKC = (L == 1) ? 2 : 16;   // x-part K chunks (K/32)
  constexpr int NKC = XKC + 16;            // total K chunks
  constexpr size_t SLOT = (size_t)NB * HS; // halves per h slot
  constexpr bool PLAIN_H = (L == 1) || HIST;

  extern __shared__ __align__(16) char smem[];
  f16* Bl = (f16*)smem;
  float* zl = (float*)(smem + (size_t)NKC * 4096);
  __shared__ int s_gc[2];

  const int tid = threadIdx.x, lane = tid & 63, wid = tid >> 6;
  const int wr4 = wid & 3, wc = wid >> 2;

  // --- XCD roster: group = physical XCD, c = arrival slot within it ---
  if (tid == 0) {
    unsigned x = xcc_id();
    int slot = atomicAdd(&roster[x], 1) & 31;
    s_gc[0] = (int)x; s_gc[1] = slot;
  }
  __syncthreads();
  const int g = s_gc[0], c = s_gc[1];
  const int b0 = g * 64;
  const int l15 = lane & 15, lk = (lane >> 4) << 3;
  const int trow = tid >> 3, tcol = (tid & 7) << 1; // gates/publish mapping

  // wrap start chunk (decorrelates the per-step L2 h-broadcast burst)
  const int kc0 = ((c >> 1) + 1) & 15;

  // --- fill B fragments (once) ---
  {
    const uint4* src = (const uint4*)wfrag + (size_t)c * NKC * 256;
    uint4* dst = (uint4*)smem;
    for (int i = tid; i < NKC * 256; i += 512) dst[i] = src[i];
  }

  // --- bias regs (interleaved cols of this WG) ---
  float bs[4][2];
#pragma unroll
  for (int ga = 0; ga < 4; ga++) {
    f32x2 bv = *(const f32x2*)(biasI + 64 * c + 16 * ga + tcol);
    bs[ga][0] = bv[0]; bs[ga][1] = bv[1];
  }

  // --- c state (thread owns row b0+trow, h-cols 16c+tcol..+2) ---
  float cst[2];
  if (L == 1) {
    cst[0] = cst[1] = 0.0f;
  } else {
    f32x2 cv = *(const f32x2*)(cInit + (size_t)(b0 + trow) * HS + 16 * c + tcol);
    cst[0] = cv[0]; cst[1] = cv[1];
  }

  const int arow = b0 + 16 * wr4 + l15;

  const f16* bbase[2];
#pragma unroll
  for (int n = 0; n < 2; n++) bbase[n] = Bl + ((size_t)(2 * wc + n) * NKC * 64 + lane) * 8;
  const f16* bh0 = bbase[0] + (size_t)XKC * 512;
  const f16* bh1 = bbase[1] + (size_t)XKC * 512;

  // per-lane blocked-layout A offset (halves): ((lk>>4)*512 + row)*16 + (lk&8)
  const size_t aoff = ((size_t)(lk >> 4) * 512 + arow) * 16 + (lk & 8);

  unsigned int* cbase = cnt + (size_t)g * TP * 16; // 64B line per (g,t)

  __syncthreads();

  for (int t = 0; t < TP; t++) {
    // ---- forced-issue x-part A loads ----
    h8 ax[XKC];
    if (L == 1) {
      const f16* xb = inp16 + ((size_t)arow * TP + t) * FIN + lk;
      ILDX(ax[0], xb, 0) ILDX(ax[1], xb, 64)
    } else {
      const f16* xp = h1s + (size_t)(t + 1) * SLOT + aoff; // prev dispatch's output
#pragma unroll
      for (int kc = 0; kc < XKC; kc++) {
        issue_ld(ax[kc], xp);
        xp += 16384;
      }
    }
    ASM_VM0; SBAR; // x regs landed

    // ---- x-part MFMA (prior-dispatch data: runs during producers' publish) ----
    f32x4 acc[2] = {};
#pragma unroll
    for (int kc = 0; kc < XKC; kc++) {
      h8 bb0 = *(const h8*)(bbase[0] + (size_t)kc * 512);
      h8 bb1 = *(const h8*)(bbase[1] + (size_t)kc * 512);
      acc[0] = __builtin_amdgcn_mfma_f32_16x16x32_f16(ax[kc], bb0, acc[0], 0, 0, 0);
      acc[1] = __builtin_amdgcn_mfma_f32_16x16x32_f16(ax[kc], bb1, acc[1], 0, 0, 0);
    }

    // ---- wait: all 32 WGs of this group published step t-1 (single word) ----
    if (t > 0) {
      const unsigned int* cp = cbase + (size_t)(t - 1) * 16;
      while (__hip_atomic_load(cp, __ATOMIC_RELAXED, __HIP_MEMORY_SCOPE_AGENT) < 32u)
        __builtin_amdgcn_s_sleep(1);
      SBAR; // nothing (esp. h loads) moves above the poll
    }

    // ---- h base (blocked layout) ----
    const f16* hb;
    if (L == 1) hb = h1s + (size_t)t * SLOT;
    else if (HIST) hb = (t == 0) ? (h1s + (size_t)TP * SLOT) : (h2s + (size_t)(t - 1) * SLOT);
    else hb = (t == 0) ? (h1s + (size_t)TP * SLOT) : (h2r + (size_t)((t - 1) & 1) * SLOT);
    const f16* hpb = hb + aoff;

    h8 hA[4], hB[4];
#define LD_H(D, P) { if constexpr (PLAIN_H) issue_ld(D, P); else issue_ldc(D, P); }
#define HB_ISSUE4(R, P)                                                        \
  {                                                                            \
    _Pragma("unroll") for (int j = 0; j < 4; j++) {                            \
      int kk = (kc0 + (P) + j) & 15;                                           \
      const f16* q = hpb + (size_t)kk * 16384;                                 \
      LD_H(R[j], q)                                                            \
    }                                                                          \
  }
#define HB_MFMA4(R, P)                                                         \
  {                                                                            \
    _Pragma("unroll") for (int j = 0; j < 4; j++) {                            \
      int kk = (kc0 + (P) + j) & 15;                                           \
      h8 bb0 = *(const h8*)(bh0 + (size_t)kk * 512);                           \
      h8 bb1 = *(const h8*)(bh1 + (size_t)kk * 512);                           \
      acc[0] = __builtin_amdgcn_mfma_f32_16x16x32_f16(R[j], bb0, acc[0], 0, 0, 0); \
      acc[1] = __builtin_amdgcn_mfma_f32_16x16x32_f16(R[j], bb1, acc[1], 0, 0, 0); \
    }                                                                          \
  }

    // ---- h-part: 4 rounds of 4, max 8 loads in flight, counted vmcnt ----
    HB_ISSUE4(hA, 0)
    HB_ISSUE4(hB, 4)
    ASM_VMC(4); SBAR;
    HB_MFMA4(hA, 0)
    HB_ISSUE4(hA, 8)
    ASM_VMC(4); SBAR;
    HB_MFMA4(hB, 4)
    HB_ISSUE4(hB, 12)
    ASM_VMC(4); SBAR;
    HB_MFMA4(hA, 8)
    ASM_VMC(0); SBAR;
    HB_MFMA4(hB, 12)
#undef HB_ISSUE4
#undef HB_MFMA4
#undef LD_H

    // ---- z exchange through LDS (reunite gate quadruples) ----
#pragma unroll
    for (int n = 0; n < 2; n++) {
      int zr = 16 * wr4 + ((lane >> 4) << 2);
      int zc_ = 32 * wc + 16 * n + l15;
#pragma unroll
      for (int r = 0; r < 4; r++) zl[(size_t)(zr + r) * 68 + zc_] = acc[n][r];
    }
    __syncthreads();

    // ---- gates (thread owns row b0+trow, h-cols 16c+tcol..+2) ----
    h2v hv;
    {
      const float* zrow = zl + (size_t)trow * 68 + tcol;
      f32x2 z0 = *(const f32x2*)(zrow + 0);
      f32x2 z1 = *(const f32x2*)(zrow + 16);
      f32x2 z2 = *(const f32x2*)(zrow + 32);
      f32x2 z3 = *(const f32x2*)(zrow + 48);
#pragma unroll
      for (int jj = 0; jj < 2; jj++) {
        float zi = z0[jj] + bs[0][jj];
        float zf = z1[jj] + bs[1][jj];
        float zg = z2[jj] + bs[2][jj];
        float zo = z3[jj] + bs[3][jj];
        float ci = sigf(zf) * cst[jj] + sigf(zi) * tanh_(zg);
        cst[jj] = ci;
        hv[jj] = (f16)(sigf(zo) * tanh_(ci));
      }
    }
    {
      f16* hsl;
      if (L == 1) hsl = h1s + (size_t)(t + 1) * SLOT;
      else if (HIST) hsl = h2s + (size_t)t * SLOT;
      else hsl = h2r + (size_t)(t & 1) * SLOT;
      f16* hp = hsl + ((size_t)c * 512 + b0 + trow) * 16 + tcol;
      // XCD-affine path: plain store -> dirty in this XCD's L2 (consumers
      // are same-XCD; fresh slot => no stale L1 copy anywhere).
      if constexpr (PLAIN_H) *(h2v*)hp = hv;
      else st_coh_h2(hp, hv); // fallback ring: write-through LLC
    }
    if (t == TP - 1) {
      f32x2 cp;
      cp[0] = cst[0]; cp[1] = cst[1];
      *(f32x2*)(cT + (size_t)(b0 + trow) * HS + 16 * c + tcol) = cp;
    }

    // ---- publish: drain stores (to L2/LLC), barrier, count ourselves in ----
    ASM_VM0;
    __syncthreads();
    if (tid == 0)
      __hip_atomic_fetch_add(cbase + (size_t)t * 16, 1u, __ATOMIC_RELAXED,
                             __HIP_MEMORY_SCOPE_AGENT);
  }
}

// ---------------------------------------------------------------------------
// Decoder: u = h2T @ dec1_Wr + dec1_b. h2T = final h2 slot base (blocked).
// ---------------------------------------------------------------------------
__global__ __launch_bounds__(256) void k_d1(const f16* __restrict__ h2T,
                                            const f16* __restrict__ wF,
                                            const float* __restrict__ bI,
                                            float* __restrict__ u) {
  const int tid = threadIdx.x, lane = tid & 63, wid = tid >> 6;
  const int wr = wid & 1, wc = wid >> 1;
  const int r0 = (blockIdx.x >> 4) * 32, ic0 = (blockIdx.x & 15) * 128;
  const int l15 = lane & 15, lk = (lane >> 4) << 3;
  const int arow = r0 + 16 * wr + l15;
  const f16* abase = h2T + ((size_t)(lk >> 4) * 512 + arow) * 16 + (lk & 8);
  const int nt0 = (ic0 >> 4) + 4 * wc;
  f32x4 acc[4] = {};
#pragma unroll
  for (int kc = 0; kc < 16; kc++) {
    h8 a = *(const h8*)(abase + (size_t)kc * 16384);
#pragma unroll
    for (int n = 0; n < 4; n++) {
      h8 b = *(const h8*)(wF + ((size_t)(nt0 + n) * 16 + kc) * 512 + (size_t)lane * 8);
      acc[n] = __builtin_amdgcn_mfma_f32_16x16x32_f16(a, b, acc[n], 0, 0, 0);
    }
  }
#pragma unroll
  for (int n = 0; n < 4; n++)
#pragma unroll
    for (int r = 0; r < 4; r++) {
      int row = r0 + 16 * wr + ((lane >> 4) << 2) + r;
      int ic = ic0 + 64 * wc + 16 * n + l15;
      u[(size_t)row * G4 + ic] = acc[n][r] + bI[ic];
    }
}

// ---------------------------------------------------------------------------
// Fused decoder: per-WG 64 (b,t) rows.
// ---------------------------------------------------------------------------
__global__ __launch_bounds__(256, 1) void k_d2(
    const f16* __restrict__ tg16, const f16* __restrict__ wk16F,
    const float* __restrict__ u, const float* __restrict__ c2T,
    const f16* __restrict__ w2F, const float* __restrict__ b2I,
    const f16* __restrict__ fcF, const float* __restrict__ fcb,
    float* __restrict__ out) {
  extern __shared__ __align__(16) char smem[];
  constexpr size_t H1OFF = 0;       // 64x512 f16, XOR-swizzled (65536 B)
  constexpr size_t C1OFF = 65536;   // 64x512 f16 (65536 B)
  constexpr size_t H2OFF = 131072;  // 4 waves x 64 x 24 f16 (12288 B)
  constexpr size_t RDOFF = 143360;  // 4 waves x 64 x 18 f32 (18432 B)

  const int tid = threadIdx.x, lane = tid & 63, wid = tid >> 6;
  const int l15 = lane & 15;
  const int r0 = blockIdx.x * 64;

  // ---- stage 1 ----
  {
    const int wr = wid & 1, wc = wid >> 1;
    h4 a[2];
#pragma unroll
    for (int m = 0; m < 2; m++)
      a[m] = *(const h4*)(tg16 + (size_t)(r0 + 32 * wr + 16 * m + l15) * FOUT +
                          ((lane >> 4) << 2));
#pragma unroll 1
    for (int hc = 0; hc < 8; hc++) {
      f32x4 acc[2][8] = {};
#pragma unroll
      for (int n = 0; n < 8; n++) {
        int ntg = 16 * hc + 8 * wc + n;
        h4 b = *(const h4*)(wk16F + ((size_t)ntg * 64 + lane) * 4);
        acc[0][n] = __builtin_amdgcn_mfma_f32_16x16x16f16(a[0], b, acc[0][n], 0, 0, 0);
        acc[1][n] = __builtin_amdgcn_mfma_f32_16x16x16f16(a[1], b, acc[1][n], 0, 0, 0);
      }
#pragma unroll
      for (int m = 0; m < 2; m++)
#pragma unroll
        for (int s = 0; s < 2; s++) {
          int qq = 4 * hc + 2 * wc + s;
          int colh = 16 * qq + l15;
          int icb = 256 * hc + 128 * wc + 64 * s + l15;
#pragma unroll
          for (int r = 0; r < 4; r++) {
            int rl = 32 * wr + 16 * m + ((lane >> 4) << 2) + r;
            int grow = r0 + rl;
            int bidx = grow / 48;
            const float* ub = u + (size_t)bidx * G4;
            float zi = acc[m][4 * s + 0][r] + ub[icb];
            float zf = acc[m][4 * s + 1][r] + ub[icb + 16];
            float zg = acc[m][4 * s + 2][r] + ub[icb + 32];
            float zo = acc[m][4 * s + 3][r] + ub[icb + 48];
            float c2v = c2T[(size_t)bidx * HS + colh];
            float c1 = sigf(zf) * c2v + sigf(zi) * tanh_(zg);
            float h1 = sigf(zo) * tanh_(c1);
            size_t hb = (((size_t)rl * 1024) + (size_t)colh * 2) ^ (size_t)((rl & 7) << 4);
            *(f16*)(smem + H1OFF + hb) = (f16)h1;
            *(f16*)(smem + C1OFF + (size_t)rl * 1024 + (size_t)colh * 2) = (f16)c1;
          }
        }
    }
  }
  __syncthreads();

  // ---- stage 2 + fc ----
  {
    const int w = wid;
    f32x4 facc[4] = {};
#pragma unroll 1
    for (int sc = 0; sc < 8; sc++) {
      f32x4 acc[4][4] = {};
#pragma unroll
      for (int kc = 0; kc < 16; kc++) {
        h8 a[4];
#pragma unroll
        for (int mt = 0; mt < 4; mt++) {
          int rl = 16 * mt + l15;
          size_t ab = (((size_t)rl * 1024) + (size_t)(kc * 32 + ((lane >> 4) << 3)) * 2) ^
                      (size_t)((rl & 7) << 4);
          a[mt] = *(const h8*)(smem + H1OFF + ab);
        }
#pragma unroll
        for (int n = 0; n < 4; n++) {
          int nt = 32 * w + 4 * sc + n;
          h8 b = *(const h8*)(w2F + ((size_t)nt * 16 + kc) * 512 + (size_t)lane * 8);
#pragma unroll
          for (int mt = 0; mt < 4; mt++)
            acc[mt][n] = __builtin_amdgcn_mfma_f32_16x16x32_f16(a[mt], b, acc[mt][n], 0, 0, 0);
        }
      }
      int qq = 8 * w + sc;
#pragma unroll
      for (int mt = 0; mt < 4; mt++)
#pragma unroll
        for (int r = 0; r < 4; r++) {
          int rl = 16 * mt + ((lane >> 4) << 2) + r;
          int colh = 16 * qq + l15;
          int ic = 512 * w + 64 * sc + l15;
          float zi = acc[mt][0][r] + b2I[ic];
          float zf = acc[mt][1][r] + b2I[ic + 16];
          float zg = acc[mt][2][r] + b2I[ic + 32];
          float zo = acc[mt][3][r] + b2I[ic + 48];
          float c1v = (float)*(const f16*)(smem + C1OFF + (size_t)rl * 1024 + (size_t)colh * 2);
          float cn = sigf(zf) * c1v + sigf(zi) * tanh_(zg);
          float h2v_ = sigf(zo) * tanh_(cn);
          *(f16*)(smem + H2OFF + (size_t)w * 3072 + (size_t)rl * 48 + (size_t)l15 * 2) = (f16)h2v_;
        }
      // fc partial for this 16-col block
#pragma unroll
      for (int mt = 0; mt < 4; mt++) {
        h4 aa = *(const h4*)(smem + H2OFF + (size_t)w * 3072 + (size_t)(16 * mt + l15) * 48 +
                             ((lane >> 4) << 3));
        h4 bb = *(const h4*)(fcF + ((size_t)qq * 64 + lane) * 4);
        facc[mt] = __builtin_amdgcn_mfma_f32_16x16x16f16(aa, bb, facc[mt], 0, 0, 0);
      }
    }
#pragma unroll
    for (int mt = 0; mt < 4; mt++)
#pragma unroll
      for (int r = 0; r < 4; r++) {
        int rl = 16 * mt + ((lane >> 4) << 2) + r;
        *(float*)(smem + RDOFF + ((size_t)w * 1152 + (size_t)rl * 18 + l15) * 4) = facc[mt][r];
      }
  }
  __syncthreads();

  // ---- cross-wave reduce + output ----
  {
    int rl = tid >> 2, c4 = (tid & 3) * 4;
    f32x4 o;
#pragma unroll
    for (int j = 0; j < 4; j++) {
      float s = 0.0f;
#pragma unroll
      for (int w = 0; w < 4; w++)
        s += *(const float*)(smem + RDOFF + ((size_t)w * 1152 + (size_t)rl * 18 + c4 + j) * 4);
      o[j] = s + fcb[c4 + j];
    }
    *(f32x4*)(out + (size_t)(r0 + rl) * FOUT + c4) = o;
  }
}

// ---------------------------------------------------------------------------
// host
// ---------------------------------------------------------------------------
extern "C" void kernel_launch(void* const* d_in, const int* in_sizes, int n_in,
                              void* d_out, int out_size, void* d_ws, size_t ws_size,
                              hipStream_t stream) {
  const float* inp     = (const float*)d_in[0];
  const float* target  = (const float*)d_in[1];
  const float* e1Wk    = (const float*)d_in[2];
  const float* e1Wr    = (const float*)d_in[3];
  const float* e1b     = (const float*)d_in[4];
  const float* e2Wk    = (const float*)d_in[5];
  const float* e2Wr    = (const float*)d_in[6];
  const float* e2b     = (const float*)d_in[7];
  const float* d1Wk    = (const float*)d_in[8];
  const float* d1Wr    = (const float*)d_in[9];
  const float* d1b     = (const float*)d_in[10];
  const float* d2Wk    = (const float*)d_in[11];
  const float* d2Wr    = (const float*)d_in[12];
  const float* d2b     = (const float*)d_in[13];
  const float* fcW     = (const float*)d_in[14];
  const float* fcb     = (const float*)d_in[15];
  float* out = (float*)d_out;

  // ---- workspace carve ----
  char* ws = (char*)d_ws;
  size_t off = 0;
  auto carve = [&](size_t bytes) { char* p = ws + off; off += bytes; return p; };
  f16*   inp16 = (f16*)carve((size_t)NB * TP * FIN * 2);        // 8.39 MB
  f16*   tg16  = (f16*)carve((size_t)NB * TFU * FOUT * 2);      // 0.79 MB
  f16*   h1s   = (f16*)carve((size_t)(TP + 1) * NB * HS * 2);   // 67.6 MB (blocked slots)
  f16*   h2r   = (f16*)carve((size_t)2 * NB * HS * 2);          // 1 MB (blocked ring)
  float* c1T   = (float*)carve((size_t)NB * HS * 4);
  float* c2T   = (float*)carve((size_t)NB * HS * 4);
  float* ubuf  = (float*)carve((size_t)NB * G4 * 4);            // 4 MB
  f16*   Wc1F  = (f16*)carve((size_t)576 * G4 * 2);
  f16*   Wc2F  = (f16*)carve((size_t)1024 * G4 * 2);
  f16*   d1WrF = (f16*)carve((size_t)512 * G4 * 2);
  f16*   W2sF  = (f16*)carve((size_t)512 * G4 * 2);
  f16*   dk16F = (f16*)carve((size_t)16 * G4 * 2);
  f16*   fcWF  = (f16*)carve((size_t)512 * FOUT * 2);
  float* eB1I  = (float*)carve((size_t)G4 * 4);
  float* eB2I  = (float*)carve((size_t)G4 * 4);
  float* dB1I  = (float*)carve((size_t)G4 * 4);
  float* dB2I  = (float*)carve((size_t)G4 * 4);
  // per-(group,step) publish counters, one 64B line each: [layer][8][TP]
  unsigned int* cnt1 = (unsigned int*)carve((size_t)8 * TP * 64);
  unsigned int* cnt2 = (unsigned int*)carve((size_t)8 * TP * 64);
  int*   roster = (int*)carve(256);                             // [0..7] L1, [8..15] L2 (+pad)
  // optional 128-slot h2 history (enables L2-shared plain h loads in enc2)
  const size_t H2S_BYTES = (size_t)TP * NB * HS * 2;            // 67.1 MB
  bool hist = (ws_size >= off + H2S_BYTES);
  f16* h2s = hist ? (f16*)carve(H2S_BYTES) : nullptr;
  (void)n_in; (void)in_sizes; (void)out_size;

  constexpr int LDS_E1 = 18 * 4096 + 64 * 68 * 4;  // 91136
  constexpr int LDS_E2 = 32 * 4096 + 64 * 68 * 4;  // 148480
  constexpr int LDS_D2 = 143360 + 18432;           // 161792
  {
    void (*p1)(const f16*, const float*, f16*, f16*, f16*, float*, const float*, const f16*,
               unsigned int*, int*) = k_enc<1, true>;
    void (*p2a)(const f16*, const float*, f16*, f16*, f16*, float*, const float*, const f16*,
                unsigned int*, int*) = k_enc<2, true>;
    void (*p2b)(const f16*, const float*, f16*, f16*, f16*, float*, const float*, const f16*,
                unsigned int*, int*) = k_enc<2, false>;
    hipFuncSetAttribute((const void*)p1, hipFuncAttributeMaxDynamicSharedMemorySize, LDS_E1);
    hipFuncSetAttribute((const void*)p2a, hipFuncAttributeMaxDynamicSharedMemorySize, LDS_E2);
    hipFuncSetAttribute((const void*)p2b, hipFuncAttributeMaxDynamicSharedMemorySize, LDS_E2);
    hipFuncSetAttribute((const void*)k_d2, hipFuncAttributeMaxDynamicSharedMemorySize, LDS_D2);
  }

  // init: counters + roster = 0 (every launch: graph-replay safe),
  //       h1s slot 0 = zeros (initial hidden state)
  hipMemsetAsync(cnt1, 0, (size_t)2 * 8 * TP * 64 + 256, stream);
  hipMemsetAsync(h1s, 0, (size_t)NB * HS * 2, stream);

  // prep
  k_conv<<<4096, 256, 0, stream>>>(inp, target, inp16, tg16);
  k_bias<<<8, 256, 0, stream>>>(e1b, e2b, d1b, d2b, eB1I, eB2I, dB1I, dB2I);
  k_pack<<<576, 256, 0, stream>>>(e1Wk, e1Wr, 64, 18, 1, Wc1F);    // [Wk1;Wr1] K=576
  k_pack<<<1024, 256, 0, stream>>>(e2Wk, e2Wr, 512, 32, 1, Wc2F);  // [Wk2;Wr2] K=1024
  k_pack<<<512, 256, 0, stream>>>(d1Wr, d1Wr, 512, 16, 1, d1WrF);  // dec1_Wr K=512
  k_pack<<<512, 256, 0, stream>>>(d2Wk, d2Wr, 0, 16, 2, W2sF);     // dec2_Wk+dec2_Wr
  k_pack_dk16<<<32, 256, 0, stream>>>(d1Wk, dk16F);
  k_pack_fc<<<8, 256, 0, stream>>>(fcW, fcWF);

  // encoder (sequential by data dependence: L2 init state = L1 final state)
  k_enc<1, true><<<256, 512, LDS_E1, stream>>>(Wc1F, eB1I, h1s, h2r, h2s, c1T, nullptr,
                                               inp16, cnt1, roster);
  int* roster2 = roster + 8;
  if (hist)
    k_enc<2, true><<<256, 512, LDS_E2, stream>>>(Wc2F, eB2I, h1s, h2r, h2s, c2T, c1T,
                                                 nullptr, cnt2, roster2);
  else
    k_enc<2, false><<<256, 512, LDS_E2, stream>>>(Wc2F, eB2I, h1s, h2r, h2s, c2T, c1T,
                                                  nullptr, cnt2, roster2);

  // decoder
  const f16* h2T = hist ? (h2s + (size_t)(TP - 1) * NB * HS) : (h2r + (size_t)1 * NB * HS);
  k_d1<<<256, 256, 0, stream>>>(h2T, d1WrF, dB1I, ubuf);
  k_d2<<<384, 256, LDS_D2, stream>>>(tg16, dk16F, ubuf, c2T, W2sF, dB2I, fcWF, fcb, out);
}